// Round 13
// baseline (350.706 us; speedup 1.0000x reference)
//
#include <hip/hip_runtime.h>
#include <stdint.h>

#define M_DIM 16384
#define N_DIM 4096
#define K_DIM 4096

#define BM 256
#define BN 256
#define BK 128
#define NT (K_DIM / BK)  // 32 K-tiles

typedef int i32x4 __attribute__((ext_vector_type(4)));

// ---- async global->LDS 16B (dest = wave-uniform base, HW adds lane*16) ----
__device__ __forceinline__ void async16(const uint8_t* g, uint8_t* l) {
    __builtin_amdgcn_global_load_lds(
        (const __attribute__((address_space(1))) void*)g,
        (__attribute__((address_space(3))) void*)l,
        16, 0, 0);
}

// ------------- merged prologue: weight pack + activation quant -------------
// blocks [0, M_DIM): per-row dynamic quant of x
// blocks [M_DIM, M_DIM+16384): int32->int8 pack of weight (256 int4/block)
__global__ __launch_bounds__(256) void prep_kernel(const float* __restrict__ x,
                                                   const int* __restrict__ w32,
                                                   uint32_t* __restrict__ xq,
                                                   float* __restrict__ xscale,
                                                   uint32_t* __restrict__ w8) {
    const int b = blockIdx.x;
    const int t = threadIdx.x;
    if (b >= M_DIM) {
        const int i = (b - M_DIM) * 256 + t;
        const int4 v = reinterpret_cast<const int4*>(w32)[i];
        w8[i] = (uint32_t)(v.x & 255) | ((uint32_t)(v.y & 255) << 8) |
                ((uint32_t)(v.z & 255) << 16) | ((uint32_t)(v.w & 255) << 24);
        return;
    }
    const int m = b;
    const float4* row = reinterpret_cast<const float4*>(x + (size_t)m * K_DIM);
    float4 v[4];
    float amax = 0.0f;
#pragma unroll
    for (int i = 0; i < 4; ++i) {
        v[i] = row[t + i * 256];
        amax = fmaxf(amax, fmaxf(fmaxf(fabsf(v[i].x), fabsf(v[i].y)),
                                 fmaxf(fabsf(v[i].z), fabsf(v[i].w))));
    }
#pragma unroll
    for (int off = 32; off > 0; off >>= 1) amax = fmaxf(amax, __shfl_xor(amax, off));
    __shared__ float smax[4];
    if ((t & 63) == 0) smax[t >> 6] = amax;
    __syncthreads();
    amax = fmaxf(fmaxf(smax[0], smax[1]), fmaxf(smax[2], smax[3]));
    const float scale = amax / 127.0f;
    const float s = fmaxf(scale, 1e-8f);
    if (t == 0) xscale[m] = scale;
    uint32_t* orow = xq + (size_t)m * (K_DIM / 4);
#pragma unroll
    for (int i = 0; i < 4; ++i) {
        int q0 = __float2int_rn(v[i].x / s);
        int q1 = __float2int_rn(v[i].y / s);
        int q2 = __float2int_rn(v[i].z / s);
        int q3 = __float2int_rn(v[i].w / s);
        q0 = max(-127, min(127, q0));
        q1 = max(-127, min(127, q1));
        q2 = max(-127, min(127, q2));
        q3 = max(-127, min(127, q3));
        orow[t + i * 256] = (uint32_t)(q0 & 255) | ((uint32_t)(q1 & 255) << 8) |
                            ((uint32_t)(q2 & 255) << 16) | ((uint32_t)(q3 & 255) << 24);
    }
}

// ------- int8 GEMM: r8 pipeline + hoisted addresses + post-BAR staging -----
// 512 thr = 8 waves (2M x 4N), per-wave 128x64, mfma_i32_16x16x64.
// LDS 128KB: A0|A1|B0|B1 (32KB each, dbuf). 1 BAR + 2 lgkm + 1 vmcnt / tile.
// vs r8: (1) ALL ds_read byte offsets precomputed into per-lane locals;
// staging addresses are base + preOff[it] + kOff (kOff: one scalar add per
// tile) -> kills per-tile 64-bit address chains (VALUBusy 20%).
// (2) BOTH panels (A and B of tile T+2) staged post-BAR into the cur buffers
// just freed (all cur reads lgkm-complete pre-BAR) -> every staging load has
// a ~0.8-tile (~4000 cy) issue->drain window; VMCNT(0) pre-BAR drains only
// tile-(T+1) loads issued one tile ago. Tile head is pure read+MFMA.
// Hazard audit: reads of cur complete (LGKM0) before BAR; cur overwritten
// only after BAR -> W-A-R safe. VMCNT(0)+BAR before reading nxt -> R-A-W
// safe. 1 BAR/tile, identical across waves.
// Swizzle: LDS(row r, unit p) holds global unit p^(r&7) (pre-swizzled global
// source, linear LDS dest, XOR on ds_read). Proven 0 bank conflicts.
__global__ __launch_bounds__(512, 2) void gemm_kernel(
    const uint8_t* __restrict__ Aq, const float* __restrict__ ascale,
    const uint8_t* __restrict__ Bq, const float* __restrict__ wscale,
    float* __restrict__ out) {
    __shared__ uint8_t lds[4 * BM * BK];  // A0|A1|B0|B1
    uint8_t* ldsA0 = lds;
    uint8_t* ldsA1 = lds + BM * BK;
    uint8_t* ldsB0 = lds + 2 * BM * BK;
    uint8_t* ldsB1 = lds + 3 * BM * BK;

    const int tid = threadIdx.x;
    const int lane = tid & 63;
    const int w = tid >> 6;
    const int wr = w >> 2;     // 0..1 -> M offset wr*128
    const int wc = w & 3;      // 0..3 -> N offset wc*64
    const int lr = lane & 15;  // row within 16x16 fragment
    const int lg = lane >> 4;  // k-group 0..3 (16B each)

    // XCD-aware bijective swizzle (1024 blocks, 1024%8==0)
    const int bid = blockIdx.x;
    const int swz = (bid & 7) * (1024 / 8) + (bid >> 3);
    const size_t row0 = (size_t)(swz >> 4) * BM;  // 64 M-tiles
    const size_t col0 = (size_t)(swz & 15) * BN;  // 16 N-tiles
    const uint8_t* Ab = Aq + row0 * K_DIM;
    const uint8_t* Bb = Bq + col0 * K_DIM;

    // ---- hoisted per-lane address material (all loop-invariant) ----
    // staging: global offset for iter it = m_*K_DIM + (p_^(m_&7))*16 (+k)
    int sgOff[4];
#pragma unroll
    for (int it = 0; it < 4; ++it) {
        const int idx = it * 512 + tid;
        const int m_ = idx >> 3, p_ = idx & 7;
        sgOff[it] = m_ * K_DIM + ((p_ ^ (m_ & 7)) << 4);
    }
    // staging LDS dest offset (wave-uniform + lane*16 added by HW)
    int slOff[4];
#pragma unroll
    for (int it = 0; it < 4; ++it) slOff[it] = (it * 512 + w * 64) * 16;
    // ds_read byte offsets within a panel (XOR swizzle applied)
    int aRd[2][8], bRd[2][4];
#pragma unroll
    for (int kk = 0; kk < 2; ++kk) {
#pragma unroll
        for (int q = 0; q < 8; ++q) {
            const int r = wr * 128 + q * 16 + lr;
            const int u = kk * 4 + lg;
            aRd[kk][q] = r * BK + ((u ^ (r & 7)) << 4);
        }
#pragma unroll
        for (int p = 0; p < 4; ++p) {
            const int r = wc * 64 + p * 16 + lr;
            const int u = kk * 4 + lg;
            bRd[kk][p] = r * BK + ((u ^ (r & 7)) << 4);
        }
    }

    i32x4 acc[8][4];
#pragma unroll
    for (int i = 0; i < 8; ++i)
#pragma unroll
        for (int j = 0; j < 4; ++j) acc[i][j] = (i32x4){0, 0, 0, 0};

    // stage a full 256x128B panel; KOFF = K-byte offset of the tile
#define STAGE_P(BASE, DST, KOFF)                                                 \
    do {                                                                         \
        _Pragma("unroll") for (int it_ = 0; it_ < 4; ++it_)                      \
            async16((BASE) + (size_t)(sgOff[it_] + (KOFF)), (DST) + slOff[it_]); \
    } while (0)

    // kk-half frag reads into frag set F (A 8 + B 4 b128)
#define READ_K(BUFA, BUFB, KK, F)                                                \
    do {                                                                         \
        _Pragma("unroll") for (int q_ = 0; q_ < 8; ++q_)                         \
            afk[F][q_] = *reinterpret_cast<const i32x4*>((BUFA) + aRd[KK][q_]);  \
        _Pragma("unroll") for (int p_ = 0; p_ < 4; ++p_)                         \
            bfk[F][p_] = *reinterpret_cast<const i32x4*>((BUFB) + bRd[KK][p_]);  \
    } while (0)

#define CLUSTER(F)                                                               \
    do {                                                                         \
        __builtin_amdgcn_s_setprio(1);                                           \
        _Pragma("unroll") for (int q_ = 0; q_ < 8; ++q_)                         \
        _Pragma("unroll") for (int p_ = 0; p_ < 4; ++p_)                         \
            acc[q_][p_] = __builtin_amdgcn_mfma_i32_16x16x64_i8(                 \
                afk[F][q_], bfk[F][p_], acc[q_][p_], 0, 0, 0);                   \
        __builtin_amdgcn_s_setprio(0);                                           \
    } while (0)

#define BAR __builtin_amdgcn_s_barrier()
#define VMCNT(N) asm volatile("s_waitcnt vmcnt(" #N ")" ::: "memory")
#define LGKM0                                              \
    do {                                                   \
        asm volatile("s_waitcnt lgkmcnt(0)" ::: "memory"); \
        __builtin_amdgcn_sched_barrier(0);                 \
    } while (0)

    // tile T: cur = (CA,CB); nxt = (NA,NB); KOFF2 = (T+2 clamped)*BK
#define TILE_ONE(CA, CB, NA, NB, KOFF2)                                          \
    do {                                                                         \
        LGKM0;                   /* f0(T) ready (read at T-1 tail) */            \
        READ_K(CA, CB, 1, 1);    /* f1: drains under cluster0 */                 \
        CLUSTER(0);                                                              \
        LGKM0;                   /* f1 ready */                                  \
        VMCNT(0);                /* A(T+1),B(T+1): issued T-1 post-BAR, */       \
        BAR;                     /* ~0.8-tile window -> landed */                \
        STAGE_P(Ab, CA, KOFF2);  /* A(T+2) -> cur A (freed) */                   \
        STAGE_P(Bb, CB, KOFF2);  /* B(T+2) -> cur B (freed) */                   \
        READ_K(NA, NB, 0, 0);    /* f0(T+1): drains under cluster1 */            \
        CLUSTER(1);                                                              \
    } while (0)

    i32x4 afk[2][8], bfk[2][4];

    // ---- prologue: tiles 0,1 fully staged; tile1's 8 loads left in flight ----
    STAGE_P(Ab, ldsA0, 0);
    STAGE_P(Bb, ldsB0, 0);
    STAGE_P(Ab, ldsA1, BK);
    STAGE_P(Bb, ldsB1, BK);
    VMCNT(8);  // tile0 landed; tile1's 8 in flight
    BAR;
    READ_K(ldsA0, ldsB0, 0, 0);  // f0(0)

#pragma unroll 1
    for (int it2 = 0; it2 < NT / 2; ++it2) {
        const int T = 2 * it2;
        const int k2 = ((T + 2 < NT) ? T + 2 : NT - 1) * BK;  // clamped tail
        const int k3 = ((T + 3 < NT) ? T + 3 : NT - 1) * BK;  // (dead writes)

        TILE_ONE(ldsA0, ldsB0, ldsA1, ldsB1, k2);  // tile T
        TILE_ONE(ldsA1, ldsB1, ldsA0, ldsB0, k3);  // tile T+1
    }

    // ---- epilogue: C/D layout col = lane&15, row = (lane>>4)*4 + reg ----
    const float* asp = ascale + row0 + wr * 128;
    const float* wsp = wscale + col0 + wc * 64;
    float wsv[4];
#pragma unroll
    for (int nf = 0; nf < 4; ++nf) wsv[nf] = wsp[nf * 16 + lr];
    float* outBase = out + (row0 + wr * 128) * (size_t)N_DIM + col0 + wc * 64;
#pragma unroll
    for (int mf = 0; mf < 8; ++mf) {
#pragma unroll
        for (int j = 0; j < 4; ++j) {
            const int r = mf * 16 + lg * 4 + j;
            const float av = asp[r];
            float* orow = outBase + (size_t)r * N_DIM;
#pragma unroll
            for (int nf = 0; nf < 4; ++nf) {
                orow[nf * 16 + lr] = (float)acc[mf][nf][j] * av * wsv[nf];
            }
        }
    }
#undef STAGE_P
#undef READ_K
#undef CLUSTER
#undef TILE_ONE
#undef BAR
#undef VMCNT
#undef LGKM0
}

extern "C" void kernel_launch(void* const* d_in, const int* in_sizes, int n_in,
                              void* d_out, int out_size, void* d_ws, size_t ws_size,
                              hipStream_t stream) {
    const float* x = (const float*)d_in[0];
    const int* w32 = (const int*)d_in[1];
    const float* wscale = (const float*)d_in[2];
    float* out = (float*)d_out;

    uint8_t* ws = (uint8_t*)d_ws;
    uint32_t* xq = (uint32_t*)ws;                                  // 64 MiB
    float* xscale = (float*)(ws + (size_t)M_DIM * K_DIM);          // 64 KiB
    uint8_t* wq = ws + (size_t)M_DIM * K_DIM + (size_t)M_DIM * 4;  // 16 MiB

    // merged prologue: quant (16384 blocks) + pack (16384 blocks), one launch
    prep_kernel<<<dim3(M_DIM + N_DIM * K_DIM / 4 / 256), 256, 0, stream>>>(
        x, w32, xq, xscale, (uint32_t*)wq);
    gemm_kernel<<<dim3((M_DIM / BM) * (N_DIM / BN)), 512, 0, stream>>>(
        (const uint8_t*)xq, xscale, wq, wscale, out);
}

// Round 14
// 341.640 us; speedup vs baseline: 1.0265x; 1.0265x over previous
//
#include <hip/hip_runtime.h>
#include <stdint.h>

#define M_DIM 16384
#define N_DIM 4096
#define K_DIM 4096

#define BM 256
#define BN 256
#define BK 128
#define NT (K_DIM / BK)  // 32 K-tiles

typedef int i32x4 __attribute__((ext_vector_type(4)));

// ---- async global->LDS 16B (dest = wave-uniform base, HW adds lane*16) ----
__device__ __forceinline__ void async16(const uint8_t* g, uint8_t* l) {
    __builtin_amdgcn_global_load_lds(
        (const __attribute__((address_space(1))) void*)g,
        (__attribute__((address_space(3))) void*)l,
        16, 0, 0);
}

// ------------- merged prologue: weight pack + activation quant -------------
// blocks [0, M_DIM): per-row dynamic quant of x
// blocks [M_DIM, M_DIM+16384): int32->int8 pack of weight (256 int4/block)
__global__ __launch_bounds__(256) void prep_kernel(const float* __restrict__ x,
                                                   const int* __restrict__ w32,
                                                   uint32_t* __restrict__ xq,
                                                   float* __restrict__ xscale,
                                                   uint32_t* __restrict__ w8) {
    const int b = blockIdx.x;
    const int t = threadIdx.x;
    if (b >= M_DIM) {
        const int i = (b - M_DIM) * 256 + t;
        const int4 v = reinterpret_cast<const int4*>(w32)[i];
        w8[i] = (uint32_t)(v.x & 255) | ((uint32_t)(v.y & 255) << 8) |
                ((uint32_t)(v.z & 255) << 16) | ((uint32_t)(v.w & 255) << 24);
        return;
    }
    const int m = b;
    const float4* row = reinterpret_cast<const float4*>(x + (size_t)m * K_DIM);
    float4 v[4];
    float amax = 0.0f;
#pragma unroll
    for (int i = 0; i < 4; ++i) {
        v[i] = row[t + i * 256];
        amax = fmaxf(amax, fmaxf(fmaxf(fabsf(v[i].x), fabsf(v[i].y)),
                                 fmaxf(fabsf(v[i].z), fabsf(v[i].w))));
    }
#pragma unroll
    for (int off = 32; off > 0; off >>= 1) amax = fmaxf(amax, __shfl_xor(amax, off));
    __shared__ float smax[4];
    if ((t & 63) == 0) smax[t >> 6] = amax;
    __syncthreads();
    amax = fmaxf(fmaxf(smax[0], smax[1]), fmaxf(smax[2], smax[3]));
    const float scale = amax / 127.0f;
    const float s = fmaxf(scale, 1e-8f);
    if (t == 0) xscale[m] = scale;
    uint32_t* orow = xq + (size_t)m * (K_DIM / 4);
#pragma unroll
    for (int i = 0; i < 4; ++i) {
        int q0 = __float2int_rn(v[i].x / s);
        int q1 = __float2int_rn(v[i].y / s);
        int q2 = __float2int_rn(v[i].z / s);
        int q3 = __float2int_rn(v[i].w / s);
        q0 = max(-127, min(127, q0));
        q1 = max(-127, min(127, q1));
        q2 = max(-127, min(127, q2));
        q3 = max(-127, min(127, q3));
        orow[t + i * 256] = (uint32_t)(q0 & 255) | ((uint32_t)(q1 & 255) << 8) |
                            ((uint32_t)(q2 & 255) << 16) | ((uint32_t)(q3 & 255) << 24);
    }
}

// ------- int8 GEMM: r12 structure VERBATIM (best measured: 266.6 us) ------
// 512 thr = 8 waves (2M x 4N), per-wave 128x64, mfma_i32_16x16x64.
// LDS 128KB: A0|A1|B0|B1 (32KB each, dbuf). 1 BAR + lgkms + 1 vmcnt / tile.
// G0 waves (0-3): [LGKM; stageB; READ f1; CLUSTER f0; LGKM; VMCNT; BAR;
//                  stageA; READ f0'; CLUSTER f1]
// G1 waves (4-7): same with CLUSTER/READ swapped (anti-phase).
// Staging windows: B(T+1) issued mid-tile T (~0.7 tile before drain);
// A(T+2) issued post-BAR (~1 tile before drain).
// Swizzle: LDS(row r, unit p) holds global unit p^(r&7) (pre-swizzled global
// source, linear LDS dest, XOR on ds_read). Proven 0 bank conflicts.
__global__ __launch_bounds__(512, 2) void gemm_kernel(
    const uint8_t* __restrict__ Aq, const float* __restrict__ ascale,
    const uint8_t* __restrict__ Bq, const float* __restrict__ wscale,
    float* __restrict__ out) {
    __shared__ uint8_t lds[4 * BM * BK];  // A0|A1|B0|B1
    uint8_t* ldsA0 = lds;
    uint8_t* ldsA1 = lds + BM * BK;
    uint8_t* ldsB0 = lds + 2 * BM * BK;
    uint8_t* ldsB1 = lds + 3 * BM * BK;

    const int tid = threadIdx.x;
    const int lane = tid & 63;
    const int w = tid >> 6;
    const int wr = w >> 2;     // 0..1 -> M offset wr*128 (also phase group)
    const int wc = w & 3;      // 0..3 -> N offset wc*64
    const int lr = lane & 15;  // row within 16x16 fragment
    const int lg = lane >> 4;  // k-group 0..3 (16B each)

    // XCD-aware bijective swizzle (1024 blocks, 1024%8==0)
    const int bid = blockIdx.x;
    const int swz = (bid & 7) * (1024 / 8) + (bid >> 3);
    const size_t row0 = (size_t)(swz >> 4) * BM;  // 64 M-tiles
    const size_t col0 = (size_t)(swz & 15) * BN;  // 16 N-tiles
    const uint8_t* Ab = Aq + row0 * K_DIM;
    const uint8_t* Bb = Bq + col0 * K_DIM;

    i32x4 acc[8][4];
#pragma unroll
    for (int i = 0; i < 8; ++i)
#pragma unroll
        for (int j = 0; j < 4; ++j) acc[i][j] = (i32x4){0, 0, 0, 0};

    // stage a full 256x128B panel (32KB = 2048 x 16B units): 4 iters x 512 thr
#define STAGE_P(BASE, DST, KT)                                                   \
    do {                                                                         \
        _Pragma("unroll") for (int it_ = 0; it_ < 4; ++it_) {                    \
            const int idx_ = it_ * 512 + tid;                                    \
            const int m_ = idx_ >> 3, p_ = idx_ & 7;                             \
            async16((BASE) + (size_t)m_ * K_DIM + (KT) * BK +                    \
                        ((p_ ^ (m_ & 7)) << 4),                                  \
                    (DST) + (it_ * 512 + w * 64) * 16);                          \
        }                                                                        \
    } while (0)

    // kk-half frag reads: A 8 + B 4 b128 into frag set F
#define READ_K(BUFA, BUFB, KK, F)                                                \
    do {                                                                         \
        _Pragma("unroll") for (int q_ = 0; q_ < 8; ++q_) {                       \
            const int r_ = wr * 128 + q_ * 16 + lr;                              \
            const int u_ = (KK) * 4 + lg;                                        \
            afk[F][q_] = *reinterpret_cast<const i32x4*>(                        \
                (BUFA) + r_ * BK + ((u_ ^ (r_ & 7)) << 4));                      \
        }                                                                        \
        _Pragma("unroll") for (int p_ = 0; p_ < 4; ++p_) {                       \
            const int r_ = wc * 64 + p_ * 16 + lr;                               \
            const int u_ = (KK) * 4 + lg;                                        \
            bfk[F][p_] = *reinterpret_cast<const i32x4*>(                        \
                (BUFB) + r_ * BK + ((u_ ^ (r_ & 7)) << 4));                      \
        }                                                                        \
    } while (0)

#define CLUSTER(F)                                                               \
    do {                                                                         \
        __builtin_amdgcn_s_setprio(1);                                           \
        _Pragma("unroll") for (int q_ = 0; q_ < 8; ++q_)                         \
        _Pragma("unroll") for (int p_ = 0; p_ < 4; ++p_)                         \
            acc[q_][p_] = __builtin_amdgcn_mfma_i32_16x16x64_i8(                 \
                afk[F][q_], bfk[F][p_], acc[q_][p_], 0, 0, 0);                   \
        __builtin_amdgcn_s_setprio(0);                                           \
    } while (0)

#define BAR __builtin_amdgcn_s_barrier()
#define VMCNT(N) asm volatile("s_waitcnt vmcnt(" #N ")" ::: "memory")
#define LGKM0                                              \
    do {                                                   \
        asm volatile("s_waitcnt lgkmcnt(0)" ::: "memory"); \
        __builtin_amdgcn_sched_barrier(0);                 \
    } while (0)

    // G0 tile (read-then-cluster)
#define TILE_G0(CA, CB, NA, NB, TB, TA2)                                         \
    do {                                                                         \
        LGKM0;                 /* f0(T) ready */                                 \
        STAGE_P(Bb, NB, TB);   /* B(T+1) */                                      \
        READ_K(CA, CB, 1, 1);  /* f1 */                                          \
        CLUSTER(0);                                                              \
        LGKM0;                 /* f1 ready */                                    \
        VMCNT(0);              /* A(T+1)+B(T+1) landed */                        \
        BAR;                                                                     \
        STAGE_P(Ab, CA, TA2);  /* A(T+2) -> cur A */                             \
        READ_K(NA, NB, 0, 0);  /* f0(T+1) */                                     \
        CLUSTER(1);                                                              \
    } while (0)

    // G1 tile (cluster-then-read, anti-phase)
#define TILE_G1(CA, CB, NA, NB, TB, TA2)                                         \
    do {                                                                         \
        LGKM0;                                                                   \
        STAGE_P(Bb, NB, TB);                                                     \
        CLUSTER(0);                                                              \
        READ_K(CA, CB, 1, 1);                                                    \
        LGKM0;                                                                   \
        VMCNT(0);                                                                \
        BAR;                                                                     \
        STAGE_P(Ab, CA, TA2);                                                    \
        CLUSTER(1);                                                              \
        READ_K(NA, NB, 0, 0);                                                    \
    } while (0)

#define MAIN_LOOP(TILE_X)                                                        \
    do {                                                                         \
        READ_K(ldsA0, ldsB0, 0, 0);                                              \
        _Pragma("unroll 1") for (int it2 = 0; it2 < NT / 2; ++it2) {             \
            const int T = 2 * it2;                                               \
            const int Tp2 = (T + 2 < NT) ? T + 2 : NT - 1;                       \
            const int Tp3 = (T + 3 < NT) ? T + 3 : NT - 1;                       \
            TILE_X(ldsA0, ldsB0, ldsA1, ldsB1, T + 1, Tp2);                      \
            TILE_X(ldsA1, ldsB1, ldsA0, ldsB0, Tp2, Tp3);                        \
        }                                                                        \
    } while (0)

    i32x4 afk[2][8], bfk[2][4];

    // ---- prologue: tile0 full + A(1); leave A(1) in flight ----
    STAGE_P(Ab, ldsA0, 0);
    STAGE_P(Bb, ldsB0, 0);
    STAGE_P(Ab, ldsA1, 1);
    VMCNT(4);  // tile0 landed; A(1)'s 4 in flight
    BAR;

    if (wr == 0) {
        MAIN_LOOP(TILE_G0);
    } else {
        MAIN_LOOP(TILE_G1);
    }

    // ---- epilogue: C/D layout col = lane&15, row = (lane>>4)*4 + reg ----
    const float* asp = ascale + row0 + wr * 128;
    const float* wsp = wscale + col0 + wc * 64;
    float wsv[4];
#pragma unroll
    for (int nf = 0; nf < 4; ++nf) wsv[nf] = wsp[nf * 16 + lr];
    float* outBase = out + (row0 + wr * 128) * (size_t)N_DIM + col0 + wc * 64;
#pragma unroll
    for (int mf = 0; mf < 8; ++mf) {
#pragma unroll
        for (int j = 0; j < 4; ++j) {
            const int r = mf * 16 + lg * 4 + j;
            const float av = asp[r];
            float* orow = outBase + (size_t)r * N_DIM;
#pragma unroll
            for (int nf = 0; nf < 4; ++nf) {
                orow[nf * 16 + lr] = (float)acc[mf][nf][j] * av * wsv[nf];
            }
        }
    }
#undef STAGE_P
#undef READ_K
#undef CLUSTER
#undef TILE_G0
#undef TILE_G1
#undef MAIN_LOOP
#undef BAR
#undef VMCNT
#undef LGKM0
}

extern "C" void kernel_launch(void* const* d_in, const int* in_sizes, int n_in,
                              void* d_out, int out_size, void* d_ws, size_t ws_size,
                              hipStream_t stream) {
    const float* x = (const float*)d_in[0];
    const int* w32 = (const int*)d_in[1];
    const float* wscale = (const float*)d_in[2];
    float* out = (float*)d_out;

    uint8_t* ws = (uint8_t*)d_ws;
    uint32_t* xq = (uint32_t*)ws;                                  // 64 MiB
    float* xscale = (float*)(ws + (size_t)M_DIM * K_DIM);          // 64 KiB
    uint8_t* wq = ws + (size_t)M_DIM * K_DIM + (size_t)M_DIM * 4;  // 16 MiB

    // merged prologue: quant (16384 blocks) + pack (16384 blocks), one launch
    prep_kernel<<<dim3(M_DIM + N_DIM * K_DIM / 4 / 256), 256, 0, stream>>>(
        x, w32, xq, xscale, (uint32_t*)wq);
    gemm_kernel<<<dim3((M_DIM / BM) * (N_DIM / BN)), 512, 0, stream>>>(
        (const uint8_t*)xq, xscale, wq, wscale, out);
}